// Round 15
// baseline (213.803 us; speedup 1.0000x reference)
//
#include <hip/hip_runtime.h>

// GraphSAGE 2-layer on MI355X — persistent-B MFMA GEMMs, y-split conv2 GEMM
// (one launch, each block holds ONE weight set -> high occupancy),
// padded-bucket CSR build, biased-u8 gathers, 7-launch pipeline.
// Launches: init -> bin+cvt -> csr_build -> agg1 -> gemm1 -> conv2gemm -> agg2
// Compute:
//   xb=bf16(x), xq=u8(x*15.875+128) biased [row n = 0x80]
//   mean1b = bf16((gather-sum(xq)-128*cnt)/15.875/deg)
//   hb = bf16(relu([mean1b|xb] @ Wb1^T + b1))      (MFMA)
//   y=0: tq = u8(hb@Wb2l*15.875+128);  y=1: u = bf16(hb@Wb2r + b2)
//   out = u + gather-mean(tq)/15.875               (f32, agg epilogue)

#define NBMAX 1024
#define BCAP  2560   // bucket capacity: mean 2048 + ~11 sigma

using f32x4 = __attribute__((ext_vector_type(4))) float;
using u32x4 = __attribute__((ext_vector_type(4))) unsigned;
using s16x8 = __attribute__((ext_vector_type(8))) short;   // 8 bf16 = 4 VGPR
using s16x2 = __attribute__((ext_vector_type(2))) short;   // packed i16 pair

#define QSCALE 15.875f   // 127/8: x,t are N(0,~1); clip at |v|=8 is ~0-probability

__device__ inline unsigned short f2bf(float f) {           // RN-even, matches np/jax
    unsigned int u = __float_as_uint(f);
    unsigned int r = u + 0x7fff + ((u >> 16) & 1);
    return (unsigned short)(r >> 16);
}
__device__ inline float bflo(unsigned u) { return __uint_as_float(u << 16); }
__device__ inline float bfhi(unsigned u) { return __uint_as_float(u & 0xffff0000u); }

// ---------------- init: bucket cursors + biased-zero rows ----------------
__global__ __launch_bounds__(1024) void init_kernel(int* __restrict__ bcursor,
                                                    unsigned* __restrict__ xqz,
                                                    unsigned* __restrict__ tqz, int NB) {
    int t = threadIdx.x;
    if (t < NB) bcursor[t] = t * BCAP;
    if (t < 32) xqz[t] = 0x80808080u;          // xq zero row (128B)
    else if (t < 64) tqz[t - 32] = 0x80808080u; // tq zero row
}

// ---------------- merged bin + conversions ----------------
// Blocks [0,256): bin edges into padded buckets (LDS hist + reserved runs).
// Blocks [256,1280): x -> xb(bf16) + xq(biased u8); first 128 also weights.
__global__ __launch_bounds__(1024) void bin_cvt_kernel(
    const int* __restrict__ srci, const int* __restrict__ dsti,
    int* __restrict__ bcursor, unsigned* __restrict__ pairs, int E, int NB,
    const float* __restrict__ x, unsigned short* __restrict__ xb,
    unsigned char* __restrict__ xq, int total4,
    const float* __restrict__ W1l, const float* __restrict__ W1r,
    const float* __restrict__ W2l, const float* __restrict__ W2r,
    unsigned short* __restrict__ Wb1, unsigned short* __restrict__ Wb2l,
    unsigned short* __restrict__ Wb2r) {
    __shared__ int lh[NBMAX];
    __shared__ int lbase[NBMAX];
    if (blockIdx.x < 256) {
        // ---- bin role ----
        for (int i = threadIdx.x; i < NB; i += 1024) lh[i] = 0;
        __syncthreads();
        int chunk = (E + 255) / 256;
        int e0 = blockIdx.x * chunk;
        int e1 = min(e0 + chunk, E);
        for (int e = e0 + threadIdx.x; e < e1; e += 1024)
            atomicAdd(&lh[dsti[e] >> 7], 1);
        __syncthreads();
        for (int i = threadIdx.x; i < NB; i += 1024) {
            int c = lh[i];
            lbase[i] = c ? atomicAdd(&bcursor[i], c) : 0;
            lh[i] = 0;  // reuse as local cursor
        }
        __syncthreads();
        for (int e = e0 + threadIdx.x; e < e1; e += 1024) {
            int d = dsti[e];
            int bk = d >> 7;
            int pos = lbase[bk] + atomicAdd(&lh[bk], 1);
            pairs[pos] = ((unsigned)srci[e] << 7) | (unsigned)(d & 127);
        }
        return;
    }
    // ---- cvt role ----
    int cvtid = blockIdx.x - 256;   // 0..1023
    if (cvtid < 128) {              // weight transpose/convert: 1 elem/thread
        int idx = cvtid * 1024 + threadIdx.x;  // 0 .. 131071
        int which = idx >> 15;
        int r = idx & 32767;
        if (which == 0) {
            int o = r >> 7, kk = r & 127;
            Wb1[o * 256 + kk] = f2bf(W1l[r]);
        } else if (which == 1) {
            int o = r >> 7, kk = r & 127;
            Wb1[o * 256 + 128 + kk] = f2bf(W1r[r]);
        } else if (which == 2) {
            Wb2l[r] = f2bf(W2l[r]);
        } else {
            Wb2r[r] = f2bf(W2r[r]);
        }
    }
    int i = cvtid * 1024 + threadIdx.x;
    int stride = 1024 * 1024;
    for (; i < total4; i += stride) {
        float4 v = ((const float4*)x)[i];
        ushort4 o;
        o.x = f2bf(v.x); o.y = f2bf(v.y); o.z = f2bf(v.z); o.w = f2bf(v.w);
        ((ushort4*)xb)[i] = o;
        int q0 = max(-127, min(127, (int)rintf(v.x * QSCALE))) + 128;
        int q1 = max(-127, min(127, (int)rintf(v.y * QSCALE))) + 128;
        int q2 = max(-127, min(127, (int)rintf(v.z * QSCALE))) + 128;
        int q3 = max(-127, min(127, (int)rintf(v.w * QSCALE))) + 128;
        ((unsigned*)xq)[i] = (unsigned)q0 | ((unsigned)q1 << 8) |
                             ((unsigned)q2 << 16) | ((unsigned)q3 << 24);
    }
}

// csr entries = byte offsets (src*128 == packed pair with low 7 bits cleared).
__global__ __launch_bounds__(256) void csr_build_kernel(const unsigned* __restrict__ pairs,
                                                        const int* __restrict__ bcursor,
                                                        int2* __restrict__ offs2,
                                                        int* __restrict__ csr, int n) {
    __shared__ int ldeg[128];
    __shared__ int s[128];
    __shared__ int lcur[128];
    int b = blockIdx.x, tid = threadIdx.x;
    int lo = b * BCAP, hi = bcursor[b];
    if (tid < 128) ldeg[tid] = 0;
    __syncthreads();
    for (int i = lo + tid; i < hi; i += 256)
        atomicAdd(&ldeg[pairs[i] & 127], 1);
    __syncthreads();
    if (tid < 128) s[tid] = ldeg[tid];
    __syncthreads();
    for (int d = 1; d < 128; d <<= 1) {
        int add = (tid < 128 && tid >= d) ? s[tid - d] : 0;
        __syncthreads();
        if (tid < 128) s[tid] += add;
        __syncthreads();
    }
    if (tid < 128) {
        int excl = lo + s[tid] - ldeg[tid];
        int node = b * 128 + tid;
        if (node < n) offs2[node] = make_int2(excl, excl + ldeg[tid]);
        lcur[tid] = excl;
    }
    __syncthreads();
    for (int i = lo + tid; i < hi; i += 256) {
        unsigned p = pairs[i];
        int pos = atomicAdd(&lcur[p & 127], 1);
        csr[pos] = (int)(p & ~127u);   // src*128 byte offset
    }
}

// ---------------- aggregation: biased-u8 table ----------------
// One wave per node. Wave = 8 edge-slots x 8 lanes x 16B. v_perm unpack to
// i16 pairs; exact bias removal in epilogue.
template <bool OUT_F32>
__global__ __launch_bounds__(256) void agg_i8_kernel(const unsigned char* __restrict__ featq,
                                                     const int* __restrict__ csr,
                                                     const int2* __restrict__ offs2,
                                                     const unsigned short* __restrict__ uadd,
                                                     void* __restrict__ outp,
                                                     int n, int zoff, float dq) {
    int wave = threadIdx.x >> 6;
    int lane = threadIdx.x & 63;
    int node = blockIdx.x * 4 + wave;
    if (node >= n) return;
    int2 se = offs2[node];
    int start = se.x, end = se.y;
    int deg = end - start;
    int slot = lane >> 3;   // 0..7
    int c16 = lane & 7;     // 16B chunk within 128B row

    s16x2 accE[4], accO[4];  // even/odd bytes of each u32 (4 ch per u32)
#pragma unroll
    for (int j = 0; j < 4; ++j) { accE[j] = (s16x2){0, 0}; accO[j] = (s16x2){0, 0}; }

    auto addrow = [&](u32x4 v) {
#pragma unroll
        for (int j = 0; j < 4; ++j) {
            unsigned u = v[j];
            accE[j] += __builtin_bit_cast(s16x2, __builtin_amdgcn_perm(0u, u, 0x0C020C00u));
            accO[j] += __builtin_bit_cast(s16x2, __builtin_amdgcn_perm(0u, u, 0x0C030C01u));
        }
    };

    int nfull = deg >> 4;
    int e = start + slot;
    for (int it = 0; it < nfull; ++it, e += 16) {
        int o0 = csr[e];
        int o1 = csr[e + 8];
        u32x4 v0 = *(const u32x4*)(featq + (size_t)(unsigned)o0 + c16 * 16);
        u32x4 v1 = *(const u32x4*)(featq + (size_t)(unsigned)o1 + c16 * 16);
        addrow(v0);
        addrow(v1);
    }
    int done = start + (nfull << 4);
    int ntot = nfull << 4;
    if (done < end) {  // tail (<16 edges): zero-rows (0x80 = biased 0) for OOB
        int se0 = done + slot;
        int se1 = done + 8 + slot;
        int o0 = (se0 < end) ? csr[se0] : zoff;
        int o1 = (se1 < end) ? csr[se1] : zoff;
        u32x4 v0 = *(const u32x4*)(featq + (size_t)(unsigned)o0 + c16 * 16);
        u32x4 v1 = *(const u32x4*)(featq + (size_t)(unsigned)o1 + c16 * 16);
        addrow(v0);
        addrow(v1);
        ntot += 16;
    }

    // Butterfly sum over the 8 slots (lane bits 3,4,5), packed i16.
#pragma unroll
    for (int m = 8; m <= 32; m <<= 1) {
#pragma unroll
        for (int j = 0; j < 4; ++j) {
            accE[j] += __builtin_bit_cast(s16x2, __shfl_xor(__builtin_bit_cast(int, accE[j]), m));
            accO[j] += __builtin_bit_cast(s16x2, __shfl_xor(__builtin_bit_cast(int, accO[j]), m));
        }
    }

    if (lane < 8) {  // slot 0 writes its 16 channels
        float inv = dq / (float)max(deg, 1);
        float corr = 128.f * (float)ntot;   // exact bias removal
        if (OUT_F32) {
            // out = mean + u  (f32)
            const u32x4* up = (const u32x4*)(uadd + (size_t)node * 128 + c16 * 16);
            u32x4 ua = up[0];
            u32x4 ub = up[1];
            unsigned uw[8] = {ua.x, ua.y, ua.z, ua.w, ub.x, ub.y, ub.z, ub.w};
            float* dst = (float*)outp + (size_t)node * 128 + c16 * 16;
#pragma unroll
            for (int j = 0; j < 4; ++j) {
                f32x4 fv;
                fv[0] = ((float)accE[j][0] - corr) * inv + bflo(uw[2 * j]);
                fv[1] = ((float)accO[j][0] - corr) * inv + bfhi(uw[2 * j]);
                fv[2] = ((float)accE[j][1] - corr) * inv + bflo(uw[2 * j + 1]);
                fv[3] = ((float)accO[j][1] - corr) * inv + bfhi(uw[2 * j + 1]);
                *(f32x4*)(dst + 4 * j) = fv;
            }
        } else {
            unsigned wbuf[8];
#pragma unroll
            for (int j = 0; j < 4; ++j) {
                float f0 = ((float)accE[j][0] - corr) * inv;
                float f1 = ((float)accO[j][0] - corr) * inv;
                float f2 = ((float)accE[j][1] - corr) * inv;
                float f3 = ((float)accO[j][1] - corr) * inv;
                wbuf[2 * j]     = (unsigned)f2bf(f0) | ((unsigned)f2bf(f1) << 16);
                wbuf[2 * j + 1] = (unsigned)f2bf(f2) | ((unsigned)f2bf(f3) << 16);
            }
            u32x4* dst = (u32x4*)((unsigned short*)outp + (size_t)node * 128 + c16 * 16);
            dst[0] = (u32x4){wbuf[0], wbuf[1], wbuf[2], wbuf[3]};
            dst[1] = (u32x4){wbuf[4], wbuf[5], wbuf[6], wbuf[7]};
        }
    }
}

// ---------------- persistent-B pipelined MFMA GEMM (conv1) ----------------
// C[i,o] = sum_k A[i,k]*W[o,k]; operands swapped (W on A-port) -> lane holds
// 4 consecutive output cols. EPI: 1 = bf16(relu(acc+bias))
template <int OSTRIDE, int EPI>
__global__ __launch_bounds__(256) void gemm_persist_kernel(
    const unsigned short* __restrict__ A0, const unsigned short* __restrict__ A1,
    const unsigned short* __restrict__ Wb, const float* __restrict__ bias,
    void* __restrict__ outv, int n, int ntiles) {
    __shared__ unsigned short As[2][32 * 256];  // 2 x 16 KiB, XOR-swizzled chunks
    const int tid = threadIdx.x;
    const int w = tid >> 6, lane = tid & 63;
    const int l15 = lane & 15, lhi = lane >> 4;
    const int colbase = blockIdx.y * 128 + w * 32;

    s16x8 b[8][2];
#pragma unroll
    for (int kk = 0; kk < 8; ++kk)
#pragma unroll
        for (int cf = 0; cf < 2; ++cf)
            b[kk][cf] = *(const s16x8*)(Wb + (size_t)(colbase + cf * 16 + l15) * 256 +
                                        kk * 32 + lhi * 8);

    s16x8 st[4];
    auto stage_load = [&](int tile) {
#pragma unroll
        for (int p = 0; p < 4; ++p) {
            int chunk = p * 256 + tid;     // 1024 chunks of 16B (32 rows x 512B)
            int row = chunk >> 5;
            int cc = chunk & 31;
            int grow = tile * 32 + row;
            if (grow >= n) grow = n - 1;
            const unsigned short* src;
            if (A1) {
                src = (cc < 16) ? (A0 + (size_t)grow * 128 + cc * 8)
                                : (A1 + (size_t)grow * 128 + (cc - 16) * 8);
            } else {
                src = A0 + (size_t)grow * 256 + cc * 8;
            }
            st[p] = *(const s16x8*)src;
        }
    };
    auto stage_write = [&](int buf) {
#pragma unroll
        for (int p = 0; p < 4; ++p) {
            int chunk = p * 256 + tid;
            int row = chunk >> 5;
            int cc = chunk & 31;
            int scc = (cc & 24) | ((cc ^ (row & 7)) & 7);  // XOR swizzle
            *(s16x8*)((char*)&As[buf][0] + row * 512 + scc * 16) = st[p];
        }
    };

    int t = blockIdx.x;
    if (t >= ntiles) return;
    stage_load(t);
    stage_write(0);
    __syncthreads();
    int buf = 0;

    for (; t < ntiles; t += gridDim.x) {
        int tn = t + gridDim.x;
        bool hasNext = tn < ntiles;
        if (hasNext) stage_load(tn);

        f32x4 acc[2][2];
#pragma unroll
        for (int rf = 0; rf < 2; ++rf)
#pragma unroll
            for (int cf = 0; cf < 2; ++cf)
                acc[rf][cf] = (f32x4){0.f, 0.f, 0.f, 0.f};

#pragma unroll
        for (int kk = 0; kk < 8; ++kk) {
            s16x8 a[2];
#pragma unroll
            for (int rf = 0; rf < 2; ++rf) {
                int row = rf * 16 + l15;
                int cbase = kk * 4 + lhi;
                int scc = (cbase & 24) | ((cbase ^ (row & 7)) & 7);
                a[rf] = *(const s16x8*)((const char*)&As[buf][0] + row * 512 + scc * 16);
            }
#pragma unroll
            for (int rf = 0; rf < 2; ++rf)
#pragma unroll
                for (int cf = 0; cf < 2; ++cf)
                    acc[rf][cf] = __builtin_amdgcn_mfma_f32_16x16x32_bf16(
                        b[kk][cf], a[rf], acc[rf][cf], 0, 0, 0);  // SWAPPED
        }

        __syncthreads();
        if (hasNext) stage_write(buf ^ 1);
        __syncthreads();

#pragma unroll
        for (int rf = 0; rf < 2; ++rf) {
            int row = t * 32 + rf * 16 + l15;
            if (row >= n) continue;
#pragma unroll
            for (int cf = 0; cf < 2; ++cf) {
                int colg = colbase + cf * 16 + lhi * 4;
                f32x4 v = acc[rf][cf];
                float4 bb = *(const float4*)(bias + colg);
                v[0] += bb.x; v[1] += bb.y; v[2] += bb.z; v[3] += bb.w;
                if (EPI == 1) {
                    v[0] = fmaxf(v[0], 0.f); v[1] = fmaxf(v[1], 0.f);
                    v[2] = fmaxf(v[2], 0.f); v[3] = fmaxf(v[3], 0.f);
                }
                uint2 o;
                o.x = (unsigned)f2bf(v[0]) | ((unsigned)f2bf(v[1]) << 16);
                o.y = (unsigned)f2bf(v[2]) | ((unsigned)f2bf(v[3]) << 16);
                *(uint2*)((unsigned short*)outv + (size_t)row * OSTRIDE + colg) = o;
            }
        }
        buf ^= 1;
    }
}

// ---------------- conv2 GEMM: y-split dual (one launch) ----------------
// blockIdx.y==0: tq = u8(hb@W2l*QSCALE+128).  blockIdx.y==1: u = bf16(hb@W2r+b2).
// Each block holds ONE 64-VGPR weight strip -> ~130 VGPR -> 4-5 blocks/CU
// (vs the fused dual's ~230 VGPR / 2 blocks/CU). hb is read twice (+51MB),
// traded for 2x+ the resident waves to hide A-tile latency.
__global__ __launch_bounds__(256) void gemm_conv2_kernel(
    const unsigned short* __restrict__ A0,
    const unsigned short* __restrict__ WbL, const unsigned short* __restrict__ WbR,
    const float* __restrict__ bias,
    unsigned char* __restrict__ tq, unsigned short* __restrict__ u,
    int n, int ntiles) {
    __shared__ unsigned short As[2][32 * 256];
    const int tid = threadIdx.x;
    const int w = tid >> 6, lane = tid & 63;
    const int l15 = lane & 15, lhi = lane >> 4;
    const int colbase = w * 32;
    const bool isR = (blockIdx.y != 0);
    const unsigned short* Wb = isR ? WbR : WbL;

    s16x8 b[8][2];
#pragma unroll
    for (int kk = 0; kk < 8; ++kk)
#pragma unroll
        for (int cf = 0; cf < 2; ++cf)
            b[kk][cf] = *(const s16x8*)(Wb + (size_t)(colbase + cf * 16 + l15) * 256 +
                                        kk * 32 + lhi * 8);

    s16x8 st[4];
    auto stage_load = [&](int tile) {
#pragma unroll
        for (int p = 0; p < 4; ++p) {
            int chunk = p * 256 + tid;
            int row = chunk >> 5;
            int cc = chunk & 31;
            int grow = tile * 32 + row;
            if (grow >= n) grow = n - 1;
            st[p] = *(const s16x8*)(A0 + (size_t)grow * 256 + cc * 8);
        }
    };
    auto stage_write = [&](int buf) {
#pragma unroll
        for (int p = 0; p < 4; ++p) {
            int chunk = p * 256 + tid;
            int row = chunk >> 5;
            int cc = chunk & 31;
            int scc = (cc & 24) | ((cc ^ (row & 7)) & 7);
            *(s16x8*)((char*)&As[buf][0] + row * 512 + scc * 16) = st[p];
        }
    };

    int t = blockIdx.x;
    if (t >= ntiles) return;
    stage_load(t);
    stage_write(0);
    __syncthreads();
    int buf = 0;

    for (; t < ntiles; t += gridDim.x) {
        int tn = t + gridDim.x;
        bool hasNext = tn < ntiles;
        if (hasNext) stage_load(tn);

        f32x4 acc[2][2];
#pragma unroll
        for (int rf = 0; rf < 2; ++rf)
#pragma unroll
            for (int cf = 0; cf < 2; ++cf)
                acc[rf][cf] = (f32x4){0.f, 0.f, 0.f, 0.f};

#pragma unroll
        for (int kk = 0; kk < 8; ++kk) {
            s16x8 a[2];
#pragma unroll
            for (int rf = 0; rf < 2; ++rf) {
                int row = rf * 16 + l15;
                int cbase = kk * 4 + lhi;
                int scc = (cbase & 24) | ((cbase ^ (row & 7)) & 7);
                a[rf] = *(const s16x8*)((const char*)&As[buf][0] + row * 512 + scc * 16);
            }
#pragma unroll
            for (int rf = 0; rf < 2; ++rf)
#pragma unroll
                for (int cf = 0; cf < 2; ++cf)
                    acc[rf][cf] = __builtin_amdgcn_mfma_f32_16x16x32_bf16(
                        b[kk][cf], a[rf], acc[rf][cf], 0, 0, 0);
        }

        __syncthreads();
        if (hasNext) stage_write(buf ^ 1);
        __syncthreads();

#pragma unroll
        for (int rf = 0; rf < 2; ++rf) {
            int row = t * 32 + rf * 16 + l15;
            if (row >= n) continue;
#pragma unroll
            for (int cf = 0; cf < 2; ++cf) {
                int colg = colbase + cf * 16 + lhi * 4;
                f32x4 v = acc[rf][cf];
                if (!isR) {   // tq = biased u8 quant
                    int q0 = max(-127, min(127, (int)rintf(v[0] * QSCALE))) + 128;
                    int q1 = max(-127, min(127, (int)rintf(v[1] * QSCALE))) + 128;
                    int q2 = max(-127, min(127, (int)rintf(v[2] * QSCALE))) + 128;
                    int q3 = max(-127, min(127, (int)rintf(v[3] * QSCALE))) + 128;
                    unsigned oq = (unsigned)q0 | ((unsigned)q1 << 8) |
                                  ((unsigned)q2 << 16) | ((unsigned)q3 << 24);
                    *(unsigned*)(tq + (size_t)row * 128 + colg) = oq;
                } else {      // u = bf16(acc + b2)
                    float4 bb = *(const float4*)(bias + colg);
                    v[0] += bb.x; v[1] += bb.y; v[2] += bb.z; v[3] += bb.w;
                    uint2 ou;
                    ou.x = (unsigned)f2bf(v[0]) | ((unsigned)f2bf(v[1]) << 16);
                    ou.y = (unsigned)f2bf(v[2]) | ((unsigned)f2bf(v[3]) << 16);
                    *(uint2*)(u + (size_t)row * 128 + colg) = ou;
                }
            }
        }
        buf ^= 1;
    }
}

extern "C" void kernel_launch(void* const* d_in, const int* in_sizes, int n_in,
                              void* d_out, int out_size, void* d_ws, size_t ws_size,
                              hipStream_t stream) {
    const float* x   = (const float*)d_in[0];
    const int*   ei  = (const int*)d_in[1];
    const float* W1l = (const float*)d_in[3];
    const float* W1r = (const float*)d_in[4];
    const float* b1  = (const float*)d_in[5];
    const float* W2l = (const float*)d_in[6];
    const float* W2r = (const float*)d_in[7];
    const float* b2  = (const float*)d_in[8];

    const int n = in_sizes[0] / 128;   // 100000
    const int E = in_sizes[1] / 2;     // 1600000
    const int* srci = ei;
    const int* dsti = ei + E;
    const int NB = (n + 127) >> 7;     // buckets of 128 nodes

    char* w = (char*)d_ws;
    auto alloc = [&](size_t bytes) {
        char* p = w;
        w += (bytes + 255) & ~(size_t)255;
        return p;
    };
    int*      bcursor = (int*)alloc((size_t)NBMAX * 4);
    int2*     offs2   = (int2*)alloc((size_t)n * 8);
    unsigned* pairs   = (unsigned*)alloc((size_t)NB * BCAP * 4);
    int*      csr     = (int*)alloc((size_t)NB * BCAP * 4);
    unsigned short* Wb1   = (unsigned short*)alloc((size_t)256 * 256 * 2);
    unsigned short* Wb2l  = (unsigned short*)alloc((size_t)128 * 256 * 2);
    unsigned short* Wb2r  = (unsigned short*)alloc((size_t)128 * 256 * 2);
    unsigned short* xb    = (unsigned short*)alloc((size_t)n * 128 * 2);
    unsigned char*  xq    = (unsigned char*)alloc((size_t)(n + 1) * 128);      // +zero row
    unsigned short* mean1b= (unsigned short*)alloc((size_t)n * 128 * 2);       // also u
    unsigned short* hb    = (unsigned short*)alloc((size_t)n * 256 * 2);
    unsigned char*  tq    = (unsigned char*)alloc((size_t)(n + 1) * 128);      // +zero row
    float*          outp  = (float*)d_out;

    init_kernel<<<1, 1024, 0, stream>>>(bcursor, (unsigned*)(xq + (size_t)n * 128),
                                        (unsigned*)(tq + (size_t)n * 128), NB);
    bin_cvt_kernel<<<1280, 1024, 0, stream>>>(srci, dsti, bcursor, pairs, E, NB,
                                              x, xb, xq, n * 128 / 4,
                                              W1l, W1r, W2l, W2r, Wb1, Wb2l, Wb2r);
    csr_build_kernel<<<NB, 256, 0, stream>>>(pairs, bcursor, offs2, csr, n);

    const int ntiles = (n + 31) / 32;           // 3125
    const int zoff = n * 128;                   // zero-row byte offset
    const float dq = 1.f / QSCALE;
    // conv1
    agg_i8_kernel<false><<<(n + 3) / 4, 256, 0, stream>>>(xq, csr, offs2, nullptr, mean1b, n, zoff, dq);
    gemm_persist_kernel<256, 1><<<dim3(768, 2), 256, 0, stream>>>(mean1b, xb, Wb1, b1, hb, n, ntiles);
    // conv2: y-split GEMM (y=0 -> tq, y=1 -> u); u reuses mean1b's slot
    gemm_conv2_kernel<<<dim3(768, 2), 256, 0, stream>>>(hb, Wb2l, Wb2r, b2, tq, mean1b, n, ntiles);
    agg_i8_kernel<true><<<(n + 3) / 4, 256, 0, stream>>>(tq, csr, offs2, mean1b, outp, n, zoff, dq);
}

// Round 16
// 208.718 us; speedup vs baseline: 1.0244x; 1.0244x over previous
//
#include <hip/hip_runtime.h>

// GraphSAGE 2-layer on MI355X — persistent-B MFMA GEMMs, fused dual-B conv2
// GEMM, padded-bucket CSR build, biased-u8 gathers, 7-launch pipeline.
// (Round-14 configuration: best measured at 210.1us. Round-15's y-split
// conv2 variant tested null-to-negative and is reverted.)
// Launches: init -> bin+cvt -> csr_build -> agg1 -> gemm1 -> dual -> agg2
// Compute:
//   xb=bf16(x), xq=u8(x*15.875+128) biased [row n = 0x80]
//   mean1b = bf16((gather-sum(xq)-128*cnt)/15.875/deg)
//   hb = bf16(relu([mean1b|xb] @ Wb1^T + b1))      (MFMA)
//   {tq, u} = {u8(hb@Wb2l*15.875+128), bf16(hb@Wb2r + b2)}   (fused MFMA)
//   out = u + gather-mean(tq)/15.875               (f32, agg epilogue)

#define NBMAX 1024
#define BCAP  2560   // bucket capacity: mean 2048 + ~11 sigma

using f32x4 = __attribute__((ext_vector_type(4))) float;
using u32x4 = __attribute__((ext_vector_type(4))) unsigned;
using s16x8 = __attribute__((ext_vector_type(8))) short;   // 8 bf16 = 4 VGPR
using s16x2 = __attribute__((ext_vector_type(2))) short;   // packed i16 pair

#define QSCALE 15.875f   // 127/8: x,t are N(0,~1); clip at |v|=8 is ~0-probability

__device__ inline unsigned short f2bf(float f) {           // RN-even, matches np/jax
    unsigned int u = __float_as_uint(f);
    unsigned int r = u + 0x7fff + ((u >> 16) & 1);
    return (unsigned short)(r >> 16);
}
__device__ inline float bflo(unsigned u) { return __uint_as_float(u << 16); }
__device__ inline float bfhi(unsigned u) { return __uint_as_float(u & 0xffff0000u); }

// ---------------- init: bucket cursors + biased-zero rows ----------------
__global__ __launch_bounds__(1024) void init_kernel(int* __restrict__ bcursor,
                                                    unsigned* __restrict__ xqz,
                                                    unsigned* __restrict__ tqz, int NB) {
    int t = threadIdx.x;
    if (t < NB) bcursor[t] = t * BCAP;
    if (t < 32) xqz[t] = 0x80808080u;          // xq zero row (128B)
    else if (t < 64) tqz[t - 32] = 0x80808080u; // tq zero row
}

// ---------------- merged bin + conversions ----------------
// Blocks [0,256): bin edges into padded buckets (LDS hist + reserved runs).
// Blocks [256,1280): x -> xb(bf16) + xq(biased u8); first 128 also weights.
__global__ __launch_bounds__(1024) void bin_cvt_kernel(
    const int* __restrict__ srci, const int* __restrict__ dsti,
    int* __restrict__ bcursor, unsigned* __restrict__ pairs, int E, int NB,
    const float* __restrict__ x, unsigned short* __restrict__ xb,
    unsigned char* __restrict__ xq, int total4,
    const float* __restrict__ W1l, const float* __restrict__ W1r,
    const float* __restrict__ W2l, const float* __restrict__ W2r,
    unsigned short* __restrict__ Wb1, unsigned short* __restrict__ Wb2l,
    unsigned short* __restrict__ Wb2r) {
    __shared__ int lh[NBMAX];
    __shared__ int lbase[NBMAX];
    if (blockIdx.x < 256) {
        // ---- bin role ----
        for (int i = threadIdx.x; i < NB; i += 1024) lh[i] = 0;
        __syncthreads();
        int chunk = (E + 255) / 256;
        int e0 = blockIdx.x * chunk;
        int e1 = min(e0 + chunk, E);
        for (int e = e0 + threadIdx.x; e < e1; e += 1024)
            atomicAdd(&lh[dsti[e] >> 7], 1);
        __syncthreads();
        for (int i = threadIdx.x; i < NB; i += 1024) {
            int c = lh[i];
            lbase[i] = c ? atomicAdd(&bcursor[i], c) : 0;
            lh[i] = 0;  // reuse as local cursor
        }
        __syncthreads();
        for (int e = e0 + threadIdx.x; e < e1; e += 1024) {
            int d = dsti[e];
            int bk = d >> 7;
            int pos = lbase[bk] + atomicAdd(&lh[bk], 1);
            pairs[pos] = ((unsigned)srci[e] << 7) | (unsigned)(d & 127);
        }
        return;
    }
    // ---- cvt role ----
    int cvtid = blockIdx.x - 256;   // 0..1023
    if (cvtid < 128) {              // weight transpose/convert: 1 elem/thread
        int idx = cvtid * 1024 + threadIdx.x;  // 0 .. 131071
        int which = idx >> 15;
        int r = idx & 32767;
        if (which == 0) {
            int o = r >> 7, kk = r & 127;
            Wb1[o * 256 + kk] = f2bf(W1l[r]);
        } else if (which == 1) {
            int o = r >> 7, kk = r & 127;
            Wb1[o * 256 + 128 + kk] = f2bf(W1r[r]);
        } else if (which == 2) {
            Wb2l[r] = f2bf(W2l[r]);
        } else {
            Wb2r[r] = f2bf(W2r[r]);
        }
    }
    int i = cvtid * 1024 + threadIdx.x;
    int stride = 1024 * 1024;
    for (; i < total4; i += stride) {
        float4 v = ((const float4*)x)[i];
        ushort4 o;
        o.x = f2bf(v.x); o.y = f2bf(v.y); o.z = f2bf(v.z); o.w = f2bf(v.w);
        ((ushort4*)xb)[i] = o;
        int q0 = max(-127, min(127, (int)rintf(v.x * QSCALE))) + 128;
        int q1 = max(-127, min(127, (int)rintf(v.y * QSCALE))) + 128;
        int q2 = max(-127, min(127, (int)rintf(v.z * QSCALE))) + 128;
        int q3 = max(-127, min(127, (int)rintf(v.w * QSCALE))) + 128;
        ((unsigned*)xq)[i] = (unsigned)q0 | ((unsigned)q1 << 8) |
                             ((unsigned)q2 << 16) | ((unsigned)q3 << 24);
    }
}

// csr entries = byte offsets (src*128 == packed pair with low 7 bits cleared).
__global__ __launch_bounds__(256) void csr_build_kernel(const unsigned* __restrict__ pairs,
                                                        const int* __restrict__ bcursor,
                                                        int2* __restrict__ offs2,
                                                        int* __restrict__ csr, int n) {
    __shared__ int ldeg[128];
    __shared__ int s[128];
    __shared__ int lcur[128];
    int b = blockIdx.x, tid = threadIdx.x;
    int lo = b * BCAP, hi = bcursor[b];
    if (tid < 128) ldeg[tid] = 0;
    __syncthreads();
    for (int i = lo + tid; i < hi; i += 256)
        atomicAdd(&ldeg[pairs[i] & 127], 1);
    __syncthreads();
    if (tid < 128) s[tid] = ldeg[tid];
    __syncthreads();
    for (int d = 1; d < 128; d <<= 1) {
        int add = (tid < 128 && tid >= d) ? s[tid - d] : 0;
        __syncthreads();
        if (tid < 128) s[tid] += add;
        __syncthreads();
    }
    if (tid < 128) {
        int excl = lo + s[tid] - ldeg[tid];
        int node = b * 128 + tid;
        if (node < n) offs2[node] = make_int2(excl, excl + ldeg[tid]);
        lcur[tid] = excl;
    }
    __syncthreads();
    for (int i = lo + tid; i < hi; i += 256) {
        unsigned p = pairs[i];
        int pos = atomicAdd(&lcur[p & 127], 1);
        csr[pos] = (int)(p & ~127u);   // src*128 byte offset
    }
}

// ---------------- aggregation: biased-u8 table ----------------
// One wave per node. Wave = 8 edge-slots x 8 lanes x 16B. v_perm unpack to
// i16 pairs; exact bias removal in epilogue.
template <bool OUT_F32>
__global__ __launch_bounds__(256) void agg_i8_kernel(const unsigned char* __restrict__ featq,
                                                     const int* __restrict__ csr,
                                                     const int2* __restrict__ offs2,
                                                     const unsigned short* __restrict__ uadd,
                                                     void* __restrict__ outp,
                                                     int n, int zoff, float dq) {
    int wave = threadIdx.x >> 6;
    int lane = threadIdx.x & 63;
    int node = blockIdx.x * 4 + wave;
    if (node >= n) return;
    int2 se = offs2[node];
    int start = se.x, end = se.y;
    int deg = end - start;
    int slot = lane >> 3;   // 0..7
    int c16 = lane & 7;     // 16B chunk within 128B row

    s16x2 accE[4], accO[4];  // even/odd bytes of each u32 (4 ch per u32)
#pragma unroll
    for (int j = 0; j < 4; ++j) { accE[j] = (s16x2){0, 0}; accO[j] = (s16x2){0, 0}; }

    auto addrow = [&](u32x4 v) {
#pragma unroll
        for (int j = 0; j < 4; ++j) {
            unsigned u = v[j];
            accE[j] += __builtin_bit_cast(s16x2, __builtin_amdgcn_perm(0u, u, 0x0C020C00u));
            accO[j] += __builtin_bit_cast(s16x2, __builtin_amdgcn_perm(0u, u, 0x0C030C01u));
        }
    };

    int nfull = deg >> 4;
    int e = start + slot;
    for (int it = 0; it < nfull; ++it, e += 16) {
        int o0 = csr[e];
        int o1 = csr[e + 8];
        u32x4 v0 = *(const u32x4*)(featq + (size_t)(unsigned)o0 + c16 * 16);
        u32x4 v1 = *(const u32x4*)(featq + (size_t)(unsigned)o1 + c16 * 16);
        addrow(v0);
        addrow(v1);
    }
    int done = start + (nfull << 4);
    int ntot = nfull << 4;
    if (done < end) {  // tail (<16 edges): zero-rows (0x80 = biased 0) for OOB
        int se0 = done + slot;
        int se1 = done + 8 + slot;
        int o0 = (se0 < end) ? csr[se0] : zoff;
        int o1 = (se1 < end) ? csr[se1] : zoff;
        u32x4 v0 = *(const u32x4*)(featq + (size_t)(unsigned)o0 + c16 * 16);
        u32x4 v1 = *(const u32x4*)(featq + (size_t)(unsigned)o1 + c16 * 16);
        addrow(v0);
        addrow(v1);
        ntot += 16;
    }

    // Butterfly sum over the 8 slots (lane bits 3,4,5), packed i16.
#pragma unroll
    for (int m = 8; m <= 32; m <<= 1) {
#pragma unroll
        for (int j = 0; j < 4; ++j) {
            accE[j] += __builtin_bit_cast(s16x2, __shfl_xor(__builtin_bit_cast(int, accE[j]), m));
            accO[j] += __builtin_bit_cast(s16x2, __shfl_xor(__builtin_bit_cast(int, accO[j]), m));
        }
    }

    if (lane < 8) {  // slot 0 writes its 16 channels
        float inv = dq / (float)max(deg, 1);
        float corr = 128.f * (float)ntot;   // exact bias removal
        if (OUT_F32) {
            // out = mean + u  (f32)
            const u32x4* up = (const u32x4*)(uadd + (size_t)node * 128 + c16 * 16);
            u32x4 ua = up[0];
            u32x4 ub = up[1];
            unsigned uw[8] = {ua.x, ua.y, ua.z, ua.w, ub.x, ub.y, ub.z, ub.w};
            float* dst = (float*)outp + (size_t)node * 128 + c16 * 16;
#pragma unroll
            for (int j = 0; j < 4; ++j) {
                f32x4 fv;
                fv[0] = ((float)accE[j][0] - corr) * inv + bflo(uw[2 * j]);
                fv[1] = ((float)accO[j][0] - corr) * inv + bfhi(uw[2 * j]);
                fv[2] = ((float)accE[j][1] - corr) * inv + bflo(uw[2 * j + 1]);
                fv[3] = ((float)accO[j][1] - corr) * inv + bfhi(uw[2 * j + 1]);
                *(f32x4*)(dst + 4 * j) = fv;
            }
        } else {
            unsigned wbuf[8];
#pragma unroll
            for (int j = 0; j < 4; ++j) {
                float f0 = ((float)accE[j][0] - corr) * inv;
                float f1 = ((float)accO[j][0] - corr) * inv;
                float f2 = ((float)accE[j][1] - corr) * inv;
                float f3 = ((float)accO[j][1] - corr) * inv;
                wbuf[2 * j]     = (unsigned)f2bf(f0) | ((unsigned)f2bf(f1) << 16);
                wbuf[2 * j + 1] = (unsigned)f2bf(f2) | ((unsigned)f2bf(f3) << 16);
            }
            u32x4* dst = (u32x4*)((unsigned short*)outp + (size_t)node * 128 + c16 * 16);
            dst[0] = (u32x4){wbuf[0], wbuf[1], wbuf[2], wbuf[3]};
            dst[1] = (u32x4){wbuf[4], wbuf[5], wbuf[6], wbuf[7]};
        }
    }
}

// ---------------- persistent-B pipelined MFMA GEMM (conv1) ----------------
// C[i,o] = sum_k A[i,k]*W[o,k]; operands swapped (W on A-port) -> lane holds
// 4 consecutive output cols. EPI: 1 = bf16(relu(acc+bias))
template <int OSTRIDE, int EPI>
__global__ __launch_bounds__(256) void gemm_persist_kernel(
    const unsigned short* __restrict__ A0, const unsigned short* __restrict__ A1,
    const unsigned short* __restrict__ Wb, const float* __restrict__ bias,
    void* __restrict__ outv, int n, int ntiles) {
    __shared__ unsigned short As[2][32 * 256];  // 2 x 16 KiB, XOR-swizzled chunks
    const int tid = threadIdx.x;
    const int w = tid >> 6, lane = tid & 63;
    const int l15 = lane & 15, lhi = lane >> 4;
    const int colbase = blockIdx.y * 128 + w * 32;

    s16x8 b[8][2];
#pragma unroll
    for (int kk = 0; kk < 8; ++kk)
#pragma unroll
        for (int cf = 0; cf < 2; ++cf)
            b[kk][cf] = *(const s16x8*)(Wb + (size_t)(colbase + cf * 16 + l15) * 256 +
                                        kk * 32 + lhi * 8);

    s16x8 st[4];
    auto stage_load = [&](int tile) {
#pragma unroll
        for (int p = 0; p < 4; ++p) {
            int chunk = p * 256 + tid;     // 1024 chunks of 16B (32 rows x 512B)
            int row = chunk >> 5;
            int cc = chunk & 31;
            int grow = tile * 32 + row;
            if (grow >= n) grow = n - 1;
            const unsigned short* src;
            if (A1) {
                src = (cc < 16) ? (A0 + (size_t)grow * 128 + cc * 8)
                                : (A1 + (size_t)grow * 128 + (cc - 16) * 8);
            } else {
                src = A0 + (size_t)grow * 256 + cc * 8;
            }
            st[p] = *(const s16x8*)src;
        }
    };
    auto stage_write = [&](int buf) {
#pragma unroll
        for (int p = 0; p < 4; ++p) {
            int chunk = p * 256 + tid;
            int row = chunk >> 5;
            int cc = chunk & 31;
            int scc = (cc & 24) | ((cc ^ (row & 7)) & 7);  // XOR swizzle
            *(s16x8*)((char*)&As[buf][0] + row * 512 + scc * 16) = st[p];
        }
    };

    int t = blockIdx.x;
    if (t >= ntiles) return;
    stage_load(t);
    stage_write(0);
    __syncthreads();
    int buf = 0;

    for (; t < ntiles; t += gridDim.x) {
        int tn = t + gridDim.x;
        bool hasNext = tn < ntiles;
        if (hasNext) stage_load(tn);

        f32x4 acc[2][2];
#pragma unroll
        for (int rf = 0; rf < 2; ++rf)
#pragma unroll
            for (int cf = 0; cf < 2; ++cf)
                acc[rf][cf] = (f32x4){0.f, 0.f, 0.f, 0.f};

#pragma unroll
        for (int kk = 0; kk < 8; ++kk) {
            s16x8 a[2];
#pragma unroll
            for (int rf = 0; rf < 2; ++rf) {
                int row = rf * 16 + l15;
                int cbase = kk * 4 + lhi;
                int scc = (cbase & 24) | ((cbase ^ (row & 7)) & 7);
                a[rf] = *(const s16x8*)((const char*)&As[buf][0] + row * 512 + scc * 16);
            }
#pragma unroll
            for (int rf = 0; rf < 2; ++rf)
#pragma unroll
                for (int cf = 0; cf < 2; ++cf)
                    acc[rf][cf] = __builtin_amdgcn_mfma_f32_16x16x32_bf16(
                        b[kk][cf], a[rf], acc[rf][cf], 0, 0, 0);  // SWAPPED
        }

        __syncthreads();
        if (hasNext) stage_write(buf ^ 1);
        __syncthreads();

#pragma unroll
        for (int rf = 0; rf < 2; ++rf) {
            int row = t * 32 + rf * 16 + l15;
            if (row >= n) continue;
#pragma unroll
            for (int cf = 0; cf < 2; ++cf) {
                int colg = colbase + cf * 16 + lhi * 4;
                f32x4 v = acc[rf][cf];
                float4 bb = *(const float4*)(bias + colg);
                v[0] += bb.x; v[1] += bb.y; v[2] += bb.z; v[3] += bb.w;
                if (EPI == 1) {
                    v[0] = fmaxf(v[0], 0.f); v[1] = fmaxf(v[1], 0.f);
                    v[2] = fmaxf(v[2], 0.f); v[3] = fmaxf(v[3], 0.f);
                }
                uint2 o;
                o.x = (unsigned)f2bf(v[0]) | ((unsigned)f2bf(v[1]) << 16);
                o.y = (unsigned)f2bf(v[2]) | ((unsigned)f2bf(v[3]) << 16);
                *(uint2*)((unsigned short*)outv + (size_t)row * OSTRIDE + colg) = o;
            }
        }
        buf ^= 1;
    }
}

// ---------------- fused dual-B conv2 GEMM ----------------
// One hb pass -> t = hb@W2l (biased u8 tq) AND u = hb@W2r + b2 (bf16).
__global__ __launch_bounds__(256, 2) void gemm_dual_kernel(
    const unsigned short* __restrict__ A0,
    const unsigned short* __restrict__ WbL, const unsigned short* __restrict__ WbR,
    const float* __restrict__ bias,
    unsigned char* __restrict__ tq, unsigned short* __restrict__ u,
    int n, int ntiles) {
    __shared__ unsigned short As[2][32 * 256];
    const int tid = threadIdx.x;
    const int w = tid >> 6, lane = tid & 63;
    const int l15 = lane & 15, lhi = lane >> 4;
    const int colbase = w * 32;

    s16x8 bL[8][2], bR[8][2];
#pragma unroll
    for (int kk = 0; kk < 8; ++kk)
#pragma unroll
        for (int cf = 0; cf < 2; ++cf) {
            size_t off = (size_t)(colbase + cf * 16 + l15) * 256 + kk * 32 + lhi * 8;
            bL[kk][cf] = *(const s16x8*)(WbL + off);
            bR[kk][cf] = *(const s16x8*)(WbR + off);
        }

    s16x8 st[4];
    auto stage_load = [&](int tile) {
#pragma unroll
        for (int p = 0; p < 4; ++p) {
            int chunk = p * 256 + tid;
            int row = chunk >> 5;
            int cc = chunk & 31;
            int grow = tile * 32 + row;
            if (grow >= n) grow = n - 1;
            st[p] = *(const s16x8*)(A0 + (size_t)grow * 256 + cc * 8);
        }
    };
    auto stage_write = [&](int buf) {
#pragma unroll
        for (int p = 0; p < 4; ++p) {
            int chunk = p * 256 + tid;
            int row = chunk >> 5;
            int cc = chunk & 31;
            int scc = (cc & 24) | ((cc ^ (row & 7)) & 7);
            *(s16x8*)((char*)&As[buf][0] + row * 512 + scc * 16) = st[p];
        }
    };

    int t = blockIdx.x;
    if (t >= ntiles) return;
    stage_load(t);
    stage_write(0);
    __syncthreads();
    int buf = 0;

    for (; t < ntiles; t += gridDim.x) {
        int tn = t + gridDim.x;
        bool hasNext = tn < ntiles;
        if (hasNext) stage_load(tn);

        f32x4 accL[2][2], accR[2][2];
#pragma unroll
        for (int rf = 0; rf < 2; ++rf)
#pragma unroll
            for (int cf = 0; cf < 2; ++cf) {
                accL[rf][cf] = (f32x4){0.f, 0.f, 0.f, 0.f};
                accR[rf][cf] = (f32x4){0.f, 0.f, 0.f, 0.f};
            }

#pragma unroll
        for (int kk = 0; kk < 8; ++kk) {
            s16x8 a[2];
#pragma unroll
            for (int rf = 0; rf < 2; ++rf) {
                int row = rf * 16 + l15;
                int cbase = kk * 4 + lhi;
                int scc = (cbase & 24) | ((cbase ^ (row & 7)) & 7);
                a[rf] = *(const s16x8*)((const char*)&As[buf][0] + row * 512 + scc * 16);
            }
#pragma unroll
            for (int rf = 0; rf < 2; ++rf)
#pragma unroll
                for (int cf = 0; cf < 2; ++cf) {
                    accL[rf][cf] = __builtin_amdgcn_mfma_f32_16x16x32_bf16(
                        bL[kk][cf], a[rf], accL[rf][cf], 0, 0, 0);
                    accR[rf][cf] = __builtin_amdgcn_mfma_f32_16x16x32_bf16(
                        bR[kk][cf], a[rf], accR[rf][cf], 0, 0, 0);
                }
        }

        __syncthreads();
        if (hasNext) stage_write(buf ^ 1);
        __syncthreads();

#pragma unroll
        for (int rf = 0; rf < 2; ++rf) {
            int row = t * 32 + rf * 16 + l15;
            if (row >= n) continue;
#pragma unroll
            for (int cf = 0; cf < 2; ++cf) {
                int colg = colbase + cf * 16 + lhi * 4;
                f32x4 vL = accL[rf][cf];
                int q0 = max(-127, min(127, (int)rintf(vL[0] * QSCALE))) + 128;
                int q1 = max(-127, min(127, (int)rintf(vL[1] * QSCALE))) + 128;
                int q2 = max(-127, min(127, (int)rintf(vL[2] * QSCALE))) + 128;
                int q3 = max(-127, min(127, (int)rintf(vL[3] * QSCALE))) + 128;
                unsigned oq = (unsigned)q0 | ((unsigned)q1 << 8) |
                              ((unsigned)q2 << 16) | ((unsigned)q3 << 24);
                *(unsigned*)(tq + (size_t)row * 128 + colg) = oq;
                f32x4 vR = accR[rf][cf];
                float4 bb = *(const float4*)(bias + colg);
                vR[0] += bb.x; vR[1] += bb.y; vR[2] += bb.z; vR[3] += bb.w;
                uint2 ou;
                ou.x = (unsigned)f2bf(vR[0]) | ((unsigned)f2bf(vR[1]) << 16);
                ou.y = (unsigned)f2bf(vR[2]) | ((unsigned)f2bf(vR[3]) << 16);
                *(uint2*)(u + (size_t)row * 128 + colg) = ou;
            }
        }
        buf ^= 1;
    }
}

extern "C" void kernel_launch(void* const* d_in, const int* in_sizes, int n_in,
                              void* d_out, int out_size, void* d_ws, size_t ws_size,
                              hipStream_t stream) {
    const float* x   = (const float*)d_in[0];
    const int*   ei  = (const int*)d_in[1];
    const float* W1l = (const float*)d_in[3];
    const float* W1r = (const float*)d_in[4];
    const float* b1  = (const float*)d_in[5];
    const float* W2l = (const float*)d_in[6];
    const float* W2r = (const float*)d_in[7];
    const float* b2  = (const float*)d_in[8];

    const int n = in_sizes[0] / 128;   // 100000
    const int E = in_sizes[1] / 2;     // 1600000
    const int* srci = ei;
    const int* dsti = ei + E;
    const int NB = (n + 127) >> 7;     // buckets of 128 nodes

    char* w = (char*)d_ws;
    auto alloc = [&](size_t bytes) {
        char* p = w;
        w += (bytes + 255) & ~(size_t)255;
        return p;
    };
    int*      bcursor = (int*)alloc((size_t)NBMAX * 4);
    int2*     offs2   = (int2*)alloc((size_t)n * 8);
    unsigned* pairs   = (unsigned*)alloc((size_t)NB * BCAP * 4);
    int*      csr     = (int*)alloc((size_t)NB * BCAP * 4);
    unsigned short* Wb1   = (unsigned short*)alloc((size_t)256 * 256 * 2);
    unsigned short* Wb2l  = (unsigned short*)alloc((size_t)128 * 256 * 2);
    unsigned short* Wb2r  = (unsigned short*)alloc((size_t)128 * 256 * 2);
    unsigned short* xb    = (unsigned short*)alloc((size_t)n * 128 * 2);
    unsigned char*  xq    = (unsigned char*)alloc((size_t)(n + 1) * 128);      // +zero row
    unsigned short* mean1b= (unsigned short*)alloc((size_t)n * 128 * 2);       // also u
    unsigned short* hb    = (unsigned short*)alloc((size_t)n * 256 * 2);
    unsigned char*  tq    = (unsigned char*)alloc((size_t)(n + 1) * 128);      // +zero row
    float*          outp  = (float*)d_out;

    init_kernel<<<1, 1024, 0, stream>>>(bcursor, (unsigned*)(xq + (size_t)n * 128),
                                        (unsigned*)(tq + (size_t)n * 128), NB);
    bin_cvt_kernel<<<1280, 1024, 0, stream>>>(srci, dsti, bcursor, pairs, E, NB,
                                              x, xb, xq, n * 128 / 4,
                                              W1l, W1r, W2l, W2r, Wb1, Wb2l, Wb2r);
    csr_build_kernel<<<NB, 256, 0, stream>>>(pairs, bcursor, offs2, csr, n);

    const int ntiles = (n + 31) / 32;           // 3125
    const int zoff = n * 128;                   // zero-row byte offset
    const float dq = 1.f / QSCALE;
    // conv1
    agg_i8_kernel<false><<<(n + 3) / 4, 256, 0, stream>>>(xq, csr, offs2, nullptr, mean1b, n, zoff, dq);
    gemm_persist_kernel<256, 1><<<dim3(768, 2), 256, 0, stream>>>(mean1b, xb, Wb1, b1, hb, n, ntiles);
    // conv2: fused dual-B GEMM (single hb pass), u reuses mean1b's slot
    gemm_dual_kernel<<<512, 256, 0, stream>>>(hb, Wb2l, Wb2r, b2, tq, mean1b, n, ntiles);
    agg_i8_kernel<true><<<(n + 3) / 4, 256, 0, stream>>>(tq, csr, offs2, mean1b, outp, n, zoff, dq);
}